// Round 2
// baseline (4632.172 us; speedup 1.0000x reference)
//
#include <hip/hip_runtime.h>

#define NN 50000
#define EE 800000
#define NX 48
#define VX 16
#define NEc 32
#define VEc 16
#define HH 32

#ifdef __HIP_PLATFORM_AMD__
#define ATOMIC_ADD_F32(p, v) unsafeAtomicAdd((p), (v))
#else
#define ATOMIC_ADD_F32(p, v) atomicAdd((p), (v))
#endif

// ws layout (floats): [0..256) scalars (0=S1, 1=S2); [256..256+NN*96) upd; then node2 (NN*96)
// W2 (combined Wmu@Wh for gve/ge, 2x512 floats) is stashed in out0[0..1024):
//   written by k_prep, read by k_edge, fully overwritten by k_update afterwards.

// ---------------- prep: W2[m][v] = sum_h Wmu[m][h] * Wh[h][v]  (16x32 each, gve then ge)
__global__ void k_prep(const float* __restrict__ gveWh, const float* __restrict__ gveWmu,
                       const float* __restrict__ geWh,  const float* __restrict__ geWmu,
                       float* __restrict__ W2)
{
    int i = blockIdx.x * 256 + threadIdx.x;
    if (i < 1024) {
        int which = i >> 9;
        int r = i & 511;
        int m = r >> 5, v = r & 31;
        const float* Wmu = which ? geWmu : gveWmu;
        const float* Wh  = which ? geWh  : gveWh;
        float acc = 0.f;
        #pragma unroll 8
        for (int h = 0; h < 32; h++) acc += Wmu[m*32 + h] * Wh[h*32 + v];
        W2[i] = acc;
    }
}

// ---------------- Node GVP: s1=LN(gvp_s+s0), V1=gvp_V+V0 (unscaled), accumulate sumsq(V1)
__global__ __launch_bounds__(256) void k_node(
    const float* __restrict__ na,
    const float* __restrict__ Wh,   // 32x16
    const float* __restrict__ Wmu,  // 16x32
    const float* __restrict__ Wmw,  // 48x80
    const float* __restrict__ Wmb,  // 48
    const float* __restrict__ lng,
    const float* __restrict__ lnb,
    float* __restrict__ node2,
    float* __restrict__ S1)
{
    __shared__ float X[32][129];   // 0..47 s0 | 48..79 sh | 80..127 s1
    __shared__ float VC[32][49];   // d*16+v
    __shared__ float VH[32][97];   // d*32+h
    __shared__ float VMU[32][49];  // m*3+d
    __shared__ float MEANs[32], INVs[32];
    int tid = threadIdx.x;
    int nb = blockIdx.x * 32;
    for (int idx = tid; idx < 32*96; idx += 256) {
        int t = idx / 96, j = idx % 96;
        int n = nb + t;
        if (n < NN) {
            float v = na[(long)n*96 + j];
            if (j < 48) X[t][j] = v;
            else { int p = j - 48; VC[t][(p%3)*16 + p/3] = v; }
        }
    }
    __syncthreads();
    int t = tid & 31, c = tid >> 5;
    for (int j = 0; j < 12; j++) {
        int o = c*12 + j, d = o >> 5, h = o & 31;
        float acc = 0.f;
        #pragma unroll
        for (int v = 0; v < 16; v++) acc += Wh[h*16+v] * VC[t][d*16+v];
        VH[t][d*32+h] = acc;
    }
    __syncthreads();
    for (int j = 0; j < 4; j++) {
        int h = c*4 + j;
        float a = VH[t][h], b = VH[t][32+h], d2 = VH[t][64+h];
        X[t][48+h] = sqrtf(a*a + b*b + d2*d2);
    }
    __syncthreads();
    for (int j = 0; j < 6; j++) {
        int o = c*6 + j, m = o/3, d = o%3;
        float acc = 0.f;
        #pragma unroll 8
        for (int h = 0; h < 32; h++) acc += Wmu[m*32+h] * VH[t][d*32+h];
        VMU[t][o] = acc;
    }
    __syncthreads();
    for (int j = 0; j < 6; j++) {
        int i = c*6 + j;
        float acc = Wmb[i];
        const float* wr = Wmw + i*80;
        #pragma unroll 8
        for (int k = 0; k < 80; k++) acc += wr[k] * X[t][k];
        X[t][80+i] = fmaxf(acc, 0.f) + X[t][i];
    }
    __syncthreads();
    if (tid < 32) {
        float m = 0.f;
        #pragma unroll 8
        for (int i = 0; i < 48; i++) m += X[tid][80+i];
        m *= (1.f/48.f);
        float v = 0.f;
        #pragma unroll 8
        for (int i = 0; i < 48; i++) { float d = X[tid][80+i] - m; v += d*d; }
        MEANs[tid] = m;
        INVs[tid] = rsqrtf(v*(1.f/48.f) + 1e-5f);
    }
    __syncthreads();
    int n = nb + t;
    float ss = 0.f;
    if (n < NN) {
        float* o = node2 + (long)n*96;
        for (int j = 0; j < 6; j++) {
            int i = c*6 + j;
            o[i] = (X[t][80+i] - MEANs[t]) * INVs[t] * lng[i] + lnb[i];
        }
        for (int j = 0; j < 2; j++) {
            int m = c*2 + j;
            float a = VMU[t][m*3], b = VMU[t][m*3+1], cc = VMU[t][m*3+2];
            float nm = sqrtf(a*a + b*b + cc*cc);
            float x = nm*a + VC[t][0*16+m];
            float y = nm*b + VC[t][1*16+m];
            float z = nm*cc + VC[t][2*16+m];
            o[48+m*3] = x; o[48+m*3+1] = y; o[48+m*3+2] = z;
            ss += x*x + y*y + z*z;
        }
    }
    #pragma unroll
    for (int off = 32; off > 0; off >>= 1) ss += __shfl_down(ss, off, 64);
    if ((tid & 63) == 0) atomicAdd(S1, ss);
}

// ---------------- scale node2 V-part by global gvp_ln factor
__global__ void k_scale(float* __restrict__ node2, const float* __restrict__ S1)
{
    int i = blockIdx.x*256 + threadIdx.x;
    if (i < NN*48) {
        float scale = rsqrtf(sqrtf(*S1) * (1.f/16.f));
        int n = i/48, p = i%48;
        node2[(long)n*96 + 48 + p] *= scale;
    }
}

// ---------------- edge kernel helpers
__device__ __forceinline__ float4 ld4(const float* p) { return *(const float4*)p; }

// fused Vh (for sh) + Vmu (via combined W2) over VC; writes sh into X[lane][80+h0..]
__device__ __forceinline__ void gvp_vec(
    const float (*VC)[100], float (*X)[116], int lane, int h0, int m0,
    const float* __restrict__ Wh, const float* __restrict__ W2m, float vm[3][4])
{
    float vh[3][8];
    #pragma unroll
    for (int h = 0; h < 8; h++) vh[0][h] = vh[1][h] = vh[2][h] = 0.f;
    #pragma unroll
    for (int m = 0; m < 4; m++) vm[0][m] = vm[1][m] = vm[2][m] = 0.f;
    #pragma unroll 2
    for (int v0 = 0; v0 < 32; v0 += 4) {
        float4 c0 = ld4(&VC[lane][v0]);
        float4 c1 = ld4(&VC[lane][32 + v0]);
        float4 c2 = ld4(&VC[lane][64 + v0]);
        #pragma unroll
        for (int h = 0; h < 8; h++) {
            const float* wp = Wh + (h0 + h)*32 + v0;
            float w0 = wp[0], w1 = wp[1], w2 = wp[2], w3 = wp[3];
            vh[0][h] += w0*c0.x + w1*c0.y + w2*c0.z + w3*c0.w;
            vh[1][h] += w0*c1.x + w1*c1.y + w2*c1.z + w3*c1.w;
            vh[2][h] += w0*c2.x + w1*c2.y + w2*c2.z + w3*c2.w;
        }
        #pragma unroll
        for (int m = 0; m < 4; m++) {
            const float* wp = W2m + (m0 + m)*32 + v0;
            float w0 = wp[0], w1 = wp[1], w2 = wp[2], w3 = wp[3];
            vm[0][m] += w0*c0.x + w1*c0.y + w2*c0.z + w3*c0.w;
            vm[1][m] += w0*c1.x + w1*c1.y + w2*c1.z + w3*c1.w;
            vm[2][m] += w0*c2.x + w1*c2.y + w2*c2.z + w3*c2.w;
        }
    }
    #pragma unroll
    for (int h = 0; h < 8; h++)
        X[lane][80 + h0 + h] = sqrtf(vh[0][h]*vh[0][h] + vh[1][h]*vh[1][h] + vh[2][h]*vh[2][h]);
}

template<int NROW>
__device__ __forceinline__ void gvp_sca(
    const float (*X)[116], int lane, int r0,
    const float* __restrict__ Wmw, const float* __restrict__ Wmb, float* acc)
{
    #pragma unroll
    for (int r = 0; r < NROW; r++) acc[r] = Wmb[r0 + r];
    #pragma unroll 4
    for (int k0 = 0; k0 < 112; k0 += 4) {
        float4 x = ld4(&X[lane][k0]);
        #pragma unroll
        for (int r = 0; r < NROW; r++) {
            const float* wp = Wmw + (r0 + r)*112 + k0;
            acc[r] += wp[0]*x.x + wp[1]*x.y + wp[2]*x.z + wp[3]*x.w;
        }
    }
}

// ---------------- Edge kernel: 64 edges/block, lane=edge, rows split across 4 waves.
// Wave-uniform weight rows -> SGPR/scalar loads; b128 LDS reads amortized over 36-48 FMA.
// eidx row 0 = scatter target (segment_sum index), row 1 = gather index (node2 row).
__global__ __launch_bounds__(256, 2) void k_edge(
    const float* __restrict__ ea, const int* __restrict__ eidx,
    const float* __restrict__ node2,
    const float* __restrict__ gveWh,  // 32x32
    const float* __restrict__ gveWmw, // 48x112
    const float* __restrict__ gveWmb, // 48
    const float* __restrict__ geWh,   // 32x32
    const float* __restrict__ geWmw,  // 32x112
    const float* __restrict__ geWmb,  // 32
    const float* __restrict__ W2,     // [0..512) gve 16x32 | [512..1024) ge 16x32
    float* __restrict__ upd, float* __restrict__ out1)
{
    // strides 116/100 words: gcd(stride mod 32, 32)=4 -> 8-lane bank groups = b128 BW-minimum
    __shared__ __align__(16) float X[64][116];   // 0..47 s_n | 48..79 s_e | 80..111 sh
    __shared__ __align__(16) float VC[64][100];  // d*32 + v  (v<16 node, >=16 edge)
    __shared__ int SRCs[64], DSTs[64];

    int tid  = threadIdx.x;
    int lane = tid & 63;
    int w    = __builtin_amdgcn_readfirstlane(tid >> 6);  // wave id, SGPR
    long e0  = (long)blockIdx.x * 64;

    if (tid < 64) {
        DSTs[tid] = eidx[e0 + tid];        // edge_idx[0]: scatter target
        SRCs[tid] = eidx[EE + e0 + tid];   // edge_idx[1]: gather index
    }

    // stage edge attrs (float4, coalesced): 64*20 vec4
    #pragma unroll
    for (int it = 0; it < 5; it++) {
        int idx = tid + it*256;
        int t = idx / 20, q = idx % 20;
        float4 v = ld4(ea + (e0 + t)*80 + q*4);
        float vv[4] = {v.x, v.y, v.z, v.w};
        #pragma unroll
        for (int jj = 0; jj < 4; jj++) {
            int j = q*4 + jj;
            if (j < 32) X[t][48 + j] = vv[jj];
            else { int p = j - 32; VC[t][(p%3)*32 + 16 + p/3] = vv[jj]; }
        }
    }
    __syncthreads();   // SRCs visible
    // gather node2 rows (float4): 64*24 vec4
    #pragma unroll
    for (int it = 0; it < 6; it++) {
        int idx = tid + it*256;
        int t = idx / 24, q = idx % 24;
        float4 v = ld4(node2 + (long)SRCs[t]*96 + q*4);
        float vv[4] = {v.x, v.y, v.z, v.w};
        #pragma unroll
        for (int jj = 0; jj < 4; jj++) {
            int j = q*4 + jj;
            if (j < 48) X[t][j] = vv[jj];
            else { int p = j - 48; VC[t][(p%3)*32 + p/3] = vv[jj]; }
        }
    }
    __syncthreads();   // X[0..80), VC complete

    int dst = DSTs[lane];
    float* urow = upd + (long)dst * 96;
    int h0 = w*8, m0 = w*4;
    float vm[3][4];

    // ======== gve ========
    gvp_vec(VC, X, lane, h0, m0, gveWh, W2, vm);
    #pragma unroll
    for (int m = 0; m < 4; m++) {
        float a = vm[0][m], b = vm[1][m], c = vm[2][m];
        float nm = sqrtf(a*a + b*b + c*c);
        ATOMIC_ADD_F32(&urow[48 + (m0+m)*3 + 0], nm*a);
        ATOMIC_ADD_F32(&urow[48 + (m0+m)*3 + 1], nm*b);
        ATOMIC_ADD_F32(&urow[48 + (m0+m)*3 + 2], nm*c);
    }
    __syncthreads();   // all sh written
    {
        float acc[12];
        gvp_sca<12>(X, lane, w*12, gveWmw, gveWmb, acc);
        #pragma unroll
        for (int r = 0; r < 12; r++)
            ATOMIC_ADD_F32(&urow[w*12 + r], fmaxf(acc[r], 0.f));
    }
    __syncthreads();   // done reading gve sh before ge overwrites X[80..]

    // ======== ge ========
    gvp_vec(VC, X, lane, h0, m0, geWh, W2 + 512, vm);
    float* orow = out1 + (e0 + lane)*80;
    #pragma unroll
    for (int m = 0; m < 4; m++) {
        float a = vm[0][m], b = vm[1][m], c = vm[2][m];
        float nm = sqrtf(a*a + b*b + c*c);
        orow[32 + (m0+m)*3 + 0] = nm*a;
        orow[32 + (m0+m)*3 + 1] = nm*b;
        orow[32 + (m0+m)*3 + 2] = nm*c;
    }
    __syncthreads();   // all ge sh written
    {
        float acc[8];
        gvp_sca<8>(X, lane, w*8, geWmw, geWmb, acc);
        #pragma unroll
        for (int r = 0; r < 8; r++)
            orow[w*8 + r] = fmaxf(acc[r], 0.f);
    }
}

// ---------------- node update: su=LN(upd_s/30+s1), Vu=upd_V/30+V1 (stash unscaled), sumsq
__global__ __launch_bounds__(256) void k_update(
    const float* __restrict__ upd, const float* __restrict__ node2,
    const float* __restrict__ lng, const float* __restrict__ lnb,
    float* __restrict__ out0, float* __restrict__ S2)
{
    int n = blockIdx.x*256 + threadIdx.x;
    float ss = 0.f;
    if (n < NN) {
        const float* u = upd + (long)n*96;
        const float* p2 = node2 + (long)n*96;
        float su[48];
        float mean = 0.f;
        #pragma unroll
        for (int i = 0; i < 48; i++) { float v = u[i]*(1.f/30.f) + p2[i]; su[i] = v; mean += v; }
        mean *= (1.f/48.f);
        float var = 0.f;
        #pragma unroll
        for (int i = 0; i < 48; i++) { float d = su[i] - mean; var += d*d; }
        float inv = rsqrtf(var*(1.f/48.f) + 1e-5f);
        float* o = out0 + (long)n*96;
        #pragma unroll
        for (int i = 0; i < 48; i++) o[i] = p2[i] + (su[i]-mean)*inv*lng[i] + lnb[i];
        #pragma unroll
        for (int p = 0; p < 48; p++) {
            float v = u[48+p]*(1.f/30.f) + p2[48+p];
            o[48+p] = v;           // stash unscaled Vu
            ss += v*v;
        }
    }
    #pragma unroll
    for (int off = 32; off > 0; off >>= 1) ss += __shfl_down(ss, off, 64);
    if ((threadIdx.x & 63) == 0) atomicAdd(S2, ss);
}

// ---------------- finalize V part of output 0
__global__ void k_fin(float* __restrict__ out0, const float* __restrict__ node2,
                      const float* __restrict__ S2)
{
    int i = blockIdx.x*256 + threadIdx.x;
    if (i < NN*48) {
        float scale = rsqrtf(sqrtf(*S2) * (1.f/16.f));
        int n = i/48, p = i%48;
        long off = (long)n*96 + 48 + p;
        out0[off] = node2[off] + out0[off]*scale;
    }
}

extern "C" void kernel_launch(void* const* d_in, const int* in_sizes, int n_in,
                              void* d_out, int out_size, void* d_ws, size_t ws_size,
                              hipStream_t stream)
{
    const float* na      = (const float*)d_in[0];
    const float* ea      = (const float*)d_in[1];
    const int*   eidx    = (const int*)  d_in[2];
    const float* gv_Wh   = (const float*)d_in[3];
    const float* gv_Wmu  = (const float*)d_in[4];
    const float* gv_Wmw  = (const float*)d_in[5];
    const float* gv_Wmb  = (const float*)d_in[6];
    const float* gve_Wh  = (const float*)d_in[7];
    const float* gve_Wmu = (const float*)d_in[8];
    const float* gve_Wmw = (const float*)d_in[9];
    const float* gve_Wmb = (const float*)d_in[10];
    const float* ge_Wh   = (const float*)d_in[11];
    const float* ge_Wmu  = (const float*)d_in[12];
    const float* ge_Wmw  = (const float*)d_in[13];
    const float* ge_Wmb  = (const float*)d_in[14];
    const float* lng     = (const float*)d_in[15];
    const float* lnb     = (const float*)d_in[16];

    float* ws    = (float*)d_ws;
    float* S     = ws;                         // [0]=S1, [1]=S2
    float* upd   = ws + 256;
    float* node2 = ws + 256 + (size_t)NN*96;
    float* out0  = (float*)d_out;
    float* out1  = out0 + (size_t)NN*96;
    float* W2s   = out0;                       // stash: overwritten later by k_update

    // zero scalars + upd accumulator (ws is poisoned 0xAA before every launch)
    hipMemsetAsync(d_ws, 0, (256 + (size_t)NN*96) * sizeof(float), stream);

    k_prep<<<4, 256, 0, stream>>>(gve_Wh, gve_Wmu, ge_Wh, ge_Wmu, W2s);
    k_node<<<(NN + 31)/32, 256, 0, stream>>>(na, gv_Wh, gv_Wmu, gv_Wmw, gv_Wmb,
                                             lng, lnb, node2, S);
    k_scale<<<(NN*48 + 255)/256, 256, 0, stream>>>(node2, S);
    k_edge<<<EE/64, 256, 0, stream>>>(ea, eidx, node2,
                                      gve_Wh, gve_Wmw, gve_Wmb,
                                      ge_Wh, ge_Wmw, ge_Wmb,
                                      W2s, upd, out1);
    k_update<<<(NN + 255)/256, 256, 0, stream>>>(upd, node2, lng, lnb, out0, S + 1);
    k_fin<<<(NN*48 + 255)/256, 256, 0, stream>>>(out0, node2, S + 1);
}

// Round 3
// 1832.173 us; speedup vs baseline: 2.5282x; 2.5282x over previous
//
#include <hip/hip_runtime.h>

#define NN 50000
#define EE 800000
#define NX 48
#define VX 16
#define NEc 32
#define VEc 16
#define HH 32

#ifdef __HIP_PLATFORM_AMD__
#define ATOMIC_ADD_F32(p, v) unsafeAtomicAdd((p), (v))
#else
#define ATOMIC_ADD_F32(p, v) atomicAdd((p), (v))
#endif

// ws layout (floats):
//   [0..256)                      scalars (0=S1, 1=S2)
//   [256 .. 256+NN*96)            upd accumulator
//   [.. +NN*96)                   node2
//   then (ints): deg[NN], off[NN+1], cursor[NN], perm[EE]
// W2 (combined Wmu@Wh for gve/ge, 2x512 floats) is stashed in out0[0..1024):
//   written by k_prep, read by k_edge, overwritten later by k_update.

// ---------------- prep: W2[m][v] = sum_h Wmu[m][h] * Wh[h][v]  (16x32 each, gve then ge)
__global__ void k_prep(const float* __restrict__ gveWh, const float* __restrict__ gveWmu,
                       const float* __restrict__ geWh,  const float* __restrict__ geWmu,
                       float* __restrict__ W2)
{
    int i = blockIdx.x * 256 + threadIdx.x;
    if (i < 1024) {
        int which = i >> 9;
        int r = i & 511;
        int m = r >> 5, v = r & 31;
        const float* Wmu = which ? geWmu : gveWmu;
        const float* Wh  = which ? geWh  : gveWh;
        float acc = 0.f;
        #pragma unroll 8
        for (int h = 0; h < 32; h++) acc += Wmu[m*32 + h] * Wh[h*32 + v];
        W2[i] = acc;
    }
}

// ---------------- CSR build: histogram of dst, exclusive scan, scatter edge ids
__global__ void k_hist(const int* __restrict__ eidx, int* __restrict__ deg)
{
    int e = blockIdx.x*256 + threadIdx.x;
    if (e < EE) atomicAdd(&deg[eidx[e]], 1);
}

__global__ __launch_bounds__(256) void k_scan(const int* __restrict__ deg,
                                              int* __restrict__ off,
                                              int* __restrict__ cursor)
{
    __shared__ int part[256];
    int tid = threadIdx.x;
    const int CH = (NN + 255) / 256;
    int lo = tid * CH, hi = lo + CH; if (hi > NN) hi = NN;
    int s = 0;
    for (int i = lo; i < hi; i++) s += deg[i];
    part[tid] = s;
    __syncthreads();
    for (int st = 1; st < 256; st <<= 1) {
        int v = (tid >= st) ? part[tid - st] : 0;
        __syncthreads();
        part[tid] += v;
        __syncthreads();
    }
    int run = (tid == 0) ? 0 : part[tid - 1];
    for (int i = lo; i < hi; i++) {
        off[i] = run; cursor[i] = run;
        run += deg[i];
    }
    if (tid == 255) off[NN] = run;
}

__global__ void k_bin(const int* __restrict__ eidx, int* __restrict__ cursor,
                      int* __restrict__ perm)
{
    int e = blockIdx.x*256 + threadIdx.x;
    if (e < EE) {
        int p = atomicAdd(&cursor[eidx[e]], 1);
        perm[p] = e;
    }
}

// ---------------- Node GVP: s1=LN(gvp_s+s0), V1=gvp_V+V0 (unscaled), accumulate sumsq(V1)
__global__ __launch_bounds__(256) void k_node(
    const float* __restrict__ na,
    const float* __restrict__ Wh,   // 32x16
    const float* __restrict__ Wmu,  // 16x32
    const float* __restrict__ Wmw,  // 48x80
    const float* __restrict__ Wmb,  // 48
    const float* __restrict__ lng,
    const float* __restrict__ lnb,
    float* __restrict__ node2,
    float* __restrict__ S1)
{
    __shared__ float X[32][129];   // 0..47 s0 | 48..79 sh | 80..127 s1
    __shared__ float VC[32][49];   // d*16+v
    __shared__ float VH[32][97];   // d*32+h
    __shared__ float VMU[32][49];  // m*3+d
    __shared__ float MEANs[32], INVs[32];
    int tid = threadIdx.x;
    int nb = blockIdx.x * 32;
    for (int idx = tid; idx < 32*96; idx += 256) {
        int t = idx / 96, j = idx % 96;
        int n = nb + t;
        if (n < NN) {
            float v = na[(long)n*96 + j];
            if (j < 48) X[t][j] = v;
            else { int p = j - 48; VC[t][(p%3)*16 + p/3] = v; }
        }
    }
    __syncthreads();
    int t = tid & 31, c = tid >> 5;
    for (int j = 0; j < 12; j++) {
        int o = c*12 + j, d = o >> 5, h = o & 31;
        float acc = 0.f;
        #pragma unroll
        for (int v = 0; v < 16; v++) acc += Wh[h*16+v] * VC[t][d*16+v];
        VH[t][d*32+h] = acc;
    }
    __syncthreads();
    for (int j = 0; j < 4; j++) {
        int h = c*4 + j;
        float a = VH[t][h], b = VH[t][32+h], d2 = VH[t][64+h];
        X[t][48+h] = sqrtf(a*a + b*b + d2*d2);
    }
    __syncthreads();
    for (int j = 0; j < 6; j++) {
        int o = c*6 + j, m = o/3, d = o%3;
        float acc = 0.f;
        #pragma unroll 8
        for (int h = 0; h < 32; h++) acc += Wmu[m*32+h] * VH[t][d*32+h];
        VMU[t][o] = acc;
    }
    __syncthreads();
    for (int j = 0; j < 6; j++) {
        int i = c*6 + j;
        float acc = Wmb[i];
        const float* wr = Wmw + i*80;
        #pragma unroll 8
        for (int k = 0; k < 80; k++) acc += wr[k] * X[t][k];
        X[t][80+i] = fmaxf(acc, 0.f) + X[t][i];
    }
    __syncthreads();
    if (tid < 32) {
        float m = 0.f;
        #pragma unroll 8
        for (int i = 0; i < 48; i++) m += X[tid][80+i];
        m *= (1.f/48.f);
        float v = 0.f;
        #pragma unroll 8
        for (int i = 0; i < 48; i++) { float d = X[tid][80+i] - m; v += d*d; }
        MEANs[tid] = m;
        INVs[tid] = rsqrtf(v*(1.f/48.f) + 1e-5f);
    }
    __syncthreads();
    int n = nb + t;
    float ss = 0.f;
    if (n < NN) {
        float* o = node2 + (long)n*96;
        for (int j = 0; j < 6; j++) {
            int i = c*6 + j;
            o[i] = (X[t][80+i] - MEANs[t]) * INVs[t] * lng[i] + lnb[i];
        }
        for (int j = 0; j < 2; j++) {
            int m = c*2 + j;
            float a = VMU[t][m*3], b = VMU[t][m*3+1], cc = VMU[t][m*3+2];
            float nm = sqrtf(a*a + b*b + cc*cc);
            float x = nm*a + VC[t][0*16+m];
            float y = nm*b + VC[t][1*16+m];
            float z = nm*cc + VC[t][2*16+m];
            o[48+m*3] = x; o[48+m*3+1] = y; o[48+m*3+2] = z;
            ss += x*x + y*y + z*z;
        }
    }
    #pragma unroll
    for (int off = 32; off > 0; off >>= 1) ss += __shfl_down(ss, off, 64);
    if ((tid & 63) == 0) atomicAdd(S1, ss);
}

// ---------------- scale node2 V-part by global gvp_ln factor
__global__ void k_scale(float* __restrict__ node2, const float* __restrict__ S1)
{
    int i = blockIdx.x*256 + threadIdx.x;
    if (i < NN*48) {
        float scale = rsqrtf(sqrtf(*S1) * (1.f/16.f));
        int n = i/48, p = i%48;
        node2[(long)n*96 + 48 + p] *= scale;
    }
}

// ---------------- edge kernel helpers
__device__ __forceinline__ float4 ld4(const float* p) { return *(const float4*)p; }

// fused Vh (for sh) + Vmu (via combined W2) over VC; writes sh into X[lane][80+h0..]
__device__ __forceinline__ void gvp_vec(
    const float (*VC)[100], float (*X)[116], int lane, int h0, int m0,
    const float* __restrict__ Wh, const float* __restrict__ W2m, float vm[3][4])
{
    float vh[3][8];
    #pragma unroll
    for (int h = 0; h < 8; h++) vh[0][h] = vh[1][h] = vh[2][h] = 0.f;
    #pragma unroll
    for (int m = 0; m < 4; m++) vm[0][m] = vm[1][m] = vm[2][m] = 0.f;
    #pragma unroll 2
    for (int v0 = 0; v0 < 32; v0 += 4) {
        float4 c0 = ld4(&VC[lane][v0]);
        float4 c1 = ld4(&VC[lane][32 + v0]);
        float4 c2 = ld4(&VC[lane][64 + v0]);
        #pragma unroll
        for (int h = 0; h < 8; h++) {
            const float* wp = Wh + (h0 + h)*32 + v0;
            float w0 = wp[0], w1 = wp[1], w2 = wp[2], w3 = wp[3];
            vh[0][h] += w0*c0.x + w1*c0.y + w2*c0.z + w3*c0.w;
            vh[1][h] += w0*c1.x + w1*c1.y + w2*c1.z + w3*c1.w;
            vh[2][h] += w0*c2.x + w1*c2.y + w2*c2.z + w3*c2.w;
        }
        #pragma unroll
        for (int m = 0; m < 4; m++) {
            const float* wp = W2m + (m0 + m)*32 + v0;
            float w0 = wp[0], w1 = wp[1], w2 = wp[2], w3 = wp[3];
            vm[0][m] += w0*c0.x + w1*c0.y + w2*c0.z + w3*c0.w;
            vm[1][m] += w0*c1.x + w1*c1.y + w2*c1.z + w3*c1.w;
            vm[2][m] += w0*c2.x + w1*c2.y + w2*c2.z + w3*c2.w;
        }
    }
    #pragma unroll
    for (int h = 0; h < 8; h++)
        X[lane][80 + h0 + h] = sqrtf(vh[0][h]*vh[0][h] + vh[1][h]*vh[1][h] + vh[2][h]*vh[2][h]);
}

template<int NROW>
__device__ __forceinline__ void gvp_sca(
    const float (*X)[116], int lane, int r0,
    const float* __restrict__ Wmw, const float* __restrict__ Wmb, float* acc)
{
    #pragma unroll
    for (int r = 0; r < NROW; r++) acc[r] = Wmb[r0 + r];
    #pragma unroll 4
    for (int k0 = 0; k0 < 112; k0 += 4) {
        float4 x = ld4(&X[lane][k0]);
        #pragma unroll
        for (int r = 0; r < NROW; r++) {
            const float* wp = Wmw + (r0 + r)*112 + k0;
            acc[r] += wp[0]*x.x + wp[1]*x.y + wp[2]*x.z + wp[3]*x.w;
        }
    }
}

// ---------------- Edge kernel, dst-sorted via perm. 64 slots/block, lane=slot,
// rows split across 4 waves. Equal-dst edges are consecutive lanes: per-edge gve
// messages staged in LDS (RED), run-start lanes sum their run and issue ONE atomic
// per (run,value) -> ~16x fewer global atomics.
__global__ __launch_bounds__(256, 2) void k_edge(
    const float* __restrict__ ea, const int* __restrict__ eidx,
    const float* __restrict__ node2,
    const int*   __restrict__ perm,
    const float* __restrict__ gveWh,  // 32x32
    const float* __restrict__ gveWmw, // 48x112
    const float* __restrict__ gveWmb, // 48
    const float* __restrict__ geWh,   // 32x32
    const float* __restrict__ geWmw,  // 32x112
    const float* __restrict__ geWmb,  // 32
    const float* __restrict__ W2,     // [0..512) gve 16x32 | [512..1024) ge 16x32
    float* __restrict__ upd, float* __restrict__ out1)
{
    __shared__ __align__(16) float X[64][116];   // 0..47 s_n | 48..79 s_e | 80..111 sh
    __shared__ __align__(16) float VC[64][100];  // d*32 + v  (v<16 node, >=16 edge)
    __shared__ __align__(16) float RED[4][64][24]; // per-wave per-lane gve messages
    __shared__ int EIDl[64], SRCl[64], DSTl[64];

    int tid  = threadIdx.x;
    int lane = tid & 63;
    int w    = __builtin_amdgcn_readfirstlane(tid >> 6);
    long e0  = (long)blockIdx.x * 64;

    if (tid < 64) {
        int eid = perm[e0 + tid];
        EIDl[tid] = eid;
        DSTl[tid] = eidx[eid];        // edge_idx[0]: scatter target (sorted)
        SRCl[tid] = eidx[EE + eid];   // edge_idx[1]: gather index
    }
    __syncthreads();

    // stage edge attrs by EIDl (random 320B rows, float4)
    #pragma unroll
    for (int it = 0; it < 5; it++) {
        int idx = tid + it*256;
        int t = idx / 20, q = idx % 20;
        float4 v = ld4(ea + (long)EIDl[t]*80 + q*4);
        float vv[4] = {v.x, v.y, v.z, v.w};
        #pragma unroll
        for (int jj = 0; jj < 4; jj++) {
            int j = q*4 + jj;
            if (j < 32) X[t][48 + j] = vv[jj];
            else { int p = j - 32; VC[t][(p%3)*32 + 16 + p/3] = vv[jj]; }
        }
    }
    // gather node2 rows (float4)
    #pragma unroll
    for (int it = 0; it < 6; it++) {
        int idx = tid + it*256;
        int t = idx / 24, q = idx % 24;
        float4 v = ld4(node2 + (long)SRCl[t]*96 + q*4);
        float vv[4] = {v.x, v.y, v.z, v.w};
        #pragma unroll
        for (int jj = 0; jj < 4; jj++) {
            int j = q*4 + jj;
            if (j < 48) X[t][j] = vv[jj];
            else { int p = j - 48; VC[t][(p%3)*32 + p/3] = vv[jj]; }
        }
    }
    __syncthreads();

    int h0 = w*8, m0 = w*4;
    float vm[3][4];
    float* red = &RED[0][0][0] + (w*64 + lane)*24;

    // ======== gve vector part: stash per-edge message components in RED[12..23]
    gvp_vec(VC, X, lane, h0, m0, gveWh, W2, vm);
    #pragma unroll
    for (int m = 0; m < 4; m++) {
        float a = vm[0][m], b = vm[1][m], c = vm[2][m];
        float nm = sqrtf(a*a + b*b + c*c);
        red[12 + m*3 + 0] = nm*a;
        red[12 + m*3 + 1] = nm*b;
        red[12 + m*3 + 2] = nm*c;
    }
    __syncthreads();   // all sh written (and RED vm part)

    // ======== gve scalar part: relu per edge, stash in RED[0..11]
    {
        float acc[12];
        gvp_sca<12>(X, lane, w*12, gveWmw, gveWmb, acc);
        #pragma unroll
        for (int r = 0; r < 12; r++) red[r] = fmaxf(acc[r], 0.f);
    }
    __syncthreads();   // RED complete; gve sh reads done -> X[80..] free

    // ======== ge vector part (overwrites sh region) + out1 V writes
    gvp_vec(VC, X, lane, h0, m0, geWh, W2 + 512, vm);
    float* orow = out1 + (long)EIDl[lane]*80;
    #pragma unroll
    for (int m = 0; m < 4; m++) {
        float a = vm[0][m], b = vm[1][m], c = vm[2][m];
        float nm = sqrtf(a*a + b*b + c*c);
        orow[32 + (m0+m)*3 + 0] = nm*a;
        orow[32 + (m0+m)*3 + 1] = nm*b;
        orow[32 + (m0+m)*3 + 2] = nm*c;
    }

    // ======== gve run reduction + atomics (overlaps with other waves' ge compute)
    {
        int dl = DSTl[lane];
        bool start = (lane == 0) || (DSTl[lane-1] != dl);
        if (start) {
            float sum[24];
            #pragma unroll
            for (int v = 0; v < 24; v++) sum[v] = 0.f;
            for (int j = lane; j < 64 && DSTl[j] == dl; j++) {
                const float* rj = &RED[0][0][0] + (w*64 + j)*24;
                #pragma unroll
                for (int v = 0; v < 24; v++) sum[v] += rj[v];
            }
            float* ur = upd + (long)dl * 96;
            #pragma unroll
            for (int r = 0; r < 12; r++)
                ATOMIC_ADD_F32(&ur[w*12 + r], sum[r]);
            #pragma unroll
            for (int m = 0; m < 4; m++) {
                ATOMIC_ADD_F32(&ur[48 + (m0+m)*3 + 0], sum[12 + m*3 + 0]);
                ATOMIC_ADD_F32(&ur[48 + (m0+m)*3 + 1], sum[12 + m*3 + 1]);
                ATOMIC_ADD_F32(&ur[48 + (m0+m)*3 + 2], sum[12 + m*3 + 2]);
            }
        }
    }
    __syncthreads();   // all ge sh written

    // ======== ge scalar part
    {
        float acc[8];
        gvp_sca<8>(X, lane, w*8, geWmw, geWmb, acc);
        #pragma unroll
        for (int r = 0; r < 8; r++)
            orow[w*8 + r] = fmaxf(acc[r], 0.f);
    }
}

// ---------------- node update: su=LN(upd_s/30+s1), Vu=upd_V/30+V1 (stash unscaled), sumsq
__global__ __launch_bounds__(256) void k_update(
    const float* __restrict__ upd, const float* __restrict__ node2,
    const float* __restrict__ lng, const float* __restrict__ lnb,
    float* __restrict__ out0, float* __restrict__ S2)
{
    int n = blockIdx.x*256 + threadIdx.x;
    float ss = 0.f;
    if (n < NN) {
        const float* u = upd + (long)n*96;
        const float* p2 = node2 + (long)n*96;
        float su[48];
        float mean = 0.f;
        #pragma unroll
        for (int i = 0; i < 48; i++) { float v = u[i]*(1.f/30.f) + p2[i]; su[i] = v; mean += v; }
        mean *= (1.f/48.f);
        float var = 0.f;
        #pragma unroll
        for (int i = 0; i < 48; i++) { float d = su[i] - mean; var += d*d; }
        float inv = rsqrtf(var*(1.f/48.f) + 1e-5f);
        float* o = out0 + (long)n*96;
        #pragma unroll
        for (int i = 0; i < 48; i++) o[i] = p2[i] + (su[i]-mean)*inv*lng[i] + lnb[i];
        #pragma unroll
        for (int p = 0; p < 48; p++) {
            float v = u[48+p]*(1.f/30.f) + p2[48+p];
            o[48+p] = v;           // stash unscaled Vu
            ss += v*v;
        }
    }
    #pragma unroll
    for (int off = 32; off > 0; off >>= 1) ss += __shfl_down(ss, off, 64);
    if ((threadIdx.x & 63) == 0) atomicAdd(S2, ss);
}

// ---------------- finalize V part of output 0
__global__ void k_fin(float* __restrict__ out0, const float* __restrict__ node2,
                      const float* __restrict__ S2)
{
    int i = blockIdx.x*256 + threadIdx.x;
    if (i < NN*48) {
        float scale = rsqrtf(sqrtf(*S2) * (1.f/16.f));
        int n = i/48, p = i%48;
        long off = (long)n*96 + 48 + p;
        out0[off] = node2[off] + out0[off]*scale;
    }
}

extern "C" void kernel_launch(void* const* d_in, const int* in_sizes, int n_in,
                              void* d_out, int out_size, void* d_ws, size_t ws_size,
                              hipStream_t stream)
{
    const float* na      = (const float*)d_in[0];
    const float* ea      = (const float*)d_in[1];
    const int*   eidx    = (const int*)  d_in[2];
    const float* gv_Wh   = (const float*)d_in[3];
    const float* gv_Wmu  = (const float*)d_in[4];
    const float* gv_Wmw  = (const float*)d_in[5];
    const float* gv_Wmb  = (const float*)d_in[6];
    const float* gve_Wh  = (const float*)d_in[7];
    const float* gve_Wmu = (const float*)d_in[8];
    const float* gve_Wmw = (const float*)d_in[9];
    const float* gve_Wmb = (const float*)d_in[10];
    const float* ge_Wh   = (const float*)d_in[11];
    const float* ge_Wmu  = (const float*)d_in[12];
    const float* ge_Wmw  = (const float*)d_in[13];
    const float* ge_Wmb  = (const float*)d_in[14];
    const float* lng     = (const float*)d_in[15];
    const float* lnb     = (const float*)d_in[16];

    float* ws    = (float*)d_ws;
    float* S     = ws;                         // [0]=S1, [1]=S2
    float* upd   = ws + 256;
    float* node2 = ws + 256 + (size_t)NN*96;
    int*   deg    = (int*)(ws + 256 + (size_t)NN*96*2);
    int*   off    = deg + NN;
    int*   cursor = off + NN + 1;
    int*   perm   = cursor + NN;
    float* out0  = (float*)d_out;
    float* out1  = out0 + (size_t)NN*96;
    float* W2s   = out0;                       // stash: overwritten later by k_update

    // zero scalars + upd accumulator + deg histogram
    hipMemsetAsync(d_ws, 0, (256 + (size_t)NN*96) * sizeof(float), stream);
    hipMemsetAsync(deg, 0, (size_t)NN * sizeof(int), stream);

    k_prep<<<4, 256, 0, stream>>>(gve_Wh, gve_Wmu, ge_Wh, ge_Wmu, W2s);
    k_hist<<<(EE + 255)/256, 256, 0, stream>>>(eidx, deg);
    k_scan<<<1, 256, 0, stream>>>(deg, off, cursor);
    k_bin<<<(EE + 255)/256, 256, 0, stream>>>(eidx, cursor, perm);
    k_node<<<(NN + 31)/32, 256, 0, stream>>>(na, gv_Wh, gv_Wmu, gv_Wmw, gv_Wmb,
                                             lng, lnb, node2, S);
    k_scale<<<(NN*48 + 255)/256, 256, 0, stream>>>(node2, S);
    k_edge<<<EE/64, 256, 0, stream>>>(ea, eidx, node2, perm,
                                      gve_Wh, gve_Wmw, gve_Wmb,
                                      ge_Wh, ge_Wmw, ge_Wmb,
                                      W2s, upd, out1);
    k_update<<<(NN + 255)/256, 256, 0, stream>>>(upd, node2, lng, lnb, out0, S + 1);
    k_fin<<<(NN*48 + 255)/256, 256, 0, stream>>>(out0, node2, S + 1);
}